// Round 1
// baseline (215.808 us; speedup 1.0000x reference)
//
#include <hip/hip_runtime.h>
#include <hip/hip_bf16.h>
#include <cstdint>

#define MQ 2048
#define NC 16
#define NK 8
#define DD 256
#define H1 256
#define H2 128
#define CK 128   // NC*NK

typedef __attribute__((ext_vector_type(8))) short bf16x8;
typedef __attribute__((ext_vector_type(4))) float f32x4;

__device__ __forceinline__ unsigned short f2bf(float f) {
    union { __bf16 b; unsigned short s; } u;
    u.b = (__bf16)f;
    return u.s;
}
__device__ __forceinline__ float bf2f(unsigned short s) {
    union { __bf16 b; unsigned short s; } u;
    u.s = s;
    return (float)u.b;
}

// ---------------- kernel 0: W2^T (bf16), prototype Gram, ||q||^2 ----------------
__global__ void prep0(const float* __restrict__ query,
                      const float* __restrict__ prot,
                      const float* __restrict__ W2,
                      unsigned short* __restrict__ w2t,
                      float* __restrict__ G,
                      float* __restrict__ q2) {
    int b = blockIdx.x, t = threadIdx.x;
    if (b < 128) {
        // w2t[n][k] = W2[k][n], bf16
        int idx = b * 256 + t;          // 0..32767
        int n = idx >> 8, k = idx & 255;
        w2t[idx] = f2bf(W2[k * H2 + n]);
    } else if (b < 132) {
        // Gram: G[c][k][kp] = sum_d prot[c,k,d]*prot[c,kp,d]
        int g = (b - 128) * 256 + t;    // 0..1023
        int c = g >> 6, k = (g >> 3) & 7, kp = g & 7;
        const float4* pa = (const float4*)(prot + (c * 8 + k) * DD);
        const float4* pb = (const float4*)(prot + (c * 8 + kp) * DD);
        float s = 0.f;
        for (int i = 0; i < 64; ++i) {
            float4 x = pa[i], y = pb[i];
            s += x.x * y.x + x.y * y.y + x.z * y.z + x.w * y.w;
        }
        G[g] = s;
    } else {
        // q2[m] = ||query[m]||^2 ; 32 lanes per m
        int bb = b - 132;               // 0..255
        int ml = t >> 5, l = t & 31;
        int m = bb * 8 + ml;
        const float4* qp = (const float4*)(query + m * DD + l * 8);
        float4 a = qp[0], c4 = qp[1];
        float s = a.x * a.x + a.y * a.y + a.z * a.z + a.w * a.w
                + c4.x * c4.x + c4.y * c4.y + c4.z * c4.z + c4.w * c4.w;
        for (int off = 1; off < 32; off <<= 1) s += __shfl_xor(s, off, 32);
        if (l == 0) q2[m] = s;
    }
}

// ---------------- kernel 1: qh = q@Wq (f32), php = prot@Wp+b1 (bf16), sqp = q@P^T (f32) ----
__global__ void prep1(const float* __restrict__ query,
                      const float* __restrict__ prot,
                      const float* __restrict__ W1,
                      const float* __restrict__ b1,
                      float* __restrict__ qh,
                      unsigned short* __restrict__ php,
                      float* __restrict__ sqp) {
    __shared__ float Xs[32][33];
    __shared__ float Ws[32][65];
    int b = blockIdx.x, t = threadIdx.x;
    int sec, rb, cb;
    if (b < 256)      { sec = 0; rb = b >> 2;         cb = b & 3; }
    else if (b < 272) { sec = 1; rb = (b - 256) >> 2; cb = (b - 256) & 3; }
    else              { sec = 2; rb = (b - 272) >> 1; cb = (b - 272) & 1; }
    const float* X = (sec == 1) ? prot : query;
    int row0 = rb * 32, col0 = cb * 64;
    int c = t & 63, ry = t >> 6;
    float acc[8] = {0.f, 0.f, 0.f, 0.f, 0.f, 0.f, 0.f, 0.f};

    for (int kt = 0; kt < 8; ++kt) {
        int k0 = kt * 32;
        #pragma unroll
        for (int i = 0; i < 4; ++i) {
            int e = t + i * 256;
            int r = e >> 5, k = e & 31;
            Xs[r][k] = X[(row0 + r) * DD + k0 + k];
        }
        if (sec < 2) {
            int off = sec ? 256 : 0;
            #pragma unroll
            for (int i = 0; i < 8; ++i) {
                int e = t + i * 256;
                int kk2 = e >> 6, cc2 = e & 63;
                Ws[kk2][cc2] = W1[(k0 + kk2 + off) * H1 + col0 + cc2];
            }
        } else {
            #pragma unroll
            for (int i = 0; i < 8; ++i) {
                int e = t + i * 256;
                int cc2 = e >> 5, kk2 = e & 31;
                Ws[kk2][cc2] = prot[(col0 + cc2) * DD + k0 + kk2];
            }
        }
        __syncthreads();
        for (int kk2 = 0; kk2 < 32; ++kk2) {
            float w = Ws[kk2][c];
            #pragma unroll
            for (int j = 0; j < 8; ++j)
                acc[j] = fmaf(Xs[ry * 8 + j][kk2], w, acc[j]);
        }
        __syncthreads();
    }
    #pragma unroll
    for (int j = 0; j < 8; ++j) {
        int r = row0 + ry * 8 + j, col = col0 + c;
        if (sec == 0)      qh[r * H1 + col] = acc[j];
        else if (sec == 1) php[r * H1 + col] = f2bf(acc[j] + b1[col]);
        else               sqp[r * CK + col] = acc[j];
    }
}

// ---------------- kernel 2: fused A-build + MFMA GEMM + scores/softmax/distance ----------
__global__ __launch_bounds__(256, 2)
void fused2(const float* __restrict__ qh,
            const unsigned short* __restrict__ php,
            const unsigned short* __restrict__ w2t,
            const float* __restrict__ sqp,
            const float* __restrict__ q2,
            const float* __restrict__ G,
            const float* __restrict__ b2,
            const float* __restrict__ W3,
            float* __restrict__ out) {
    __shared__ uint4 Ash[4096];       // 128 rows x 256 bf16, XOR-swizzled, 64 KB
    __shared__ float spart[4][128];

    int t = threadIdx.x;
    int w = t >> 6, l = t & 63;
    int l15 = l & 15, l4 = l >> 4;

    // Preload this wave's B fragments (W2^T rows = its 32 output cols), kept in regs
    bf16x8 breg[8][2];
    #pragma unroll
    for (int ks = 0; ks < 8; ++ks) {
        #pragma unroll
        for (int nt = 0; nt < 2; ++nt) {
            int col = w * 32 + nt * 16 + l15;
            breg[ks][nt] = *(const bf16x8*)(w2t + col * H1 + ks * 32 + l4 * 8);
        }
    }
    float b2v[2], w3v[2];
    #pragma unroll
    for (int nt = 0; nt < 2; ++nt) {
        int col = w * 32 + nt * 16 + l15;
        b2v[nt] = b2[col];
        w3v[nt] = W3[col];
    }

    int row = t & 127, half = t >> 7;

    for (int g = 0; g < 4; ++g) {
        int m = blockIdx.x * 4 + g;

        // ---- build A[row][k] = relu(qh[m][k] + php[row][k]) in bf16, swizzled LDS ----
        {
            const float* qrow = qh + m * H1 + half * 128;
            const uint4* prow = (const uint4*)(php + row * H1 + half * 128);
            #pragma unroll
            for (int i = 0; i < 16; ++i) {
                uint4 pv = prow[i];
                float qv[8];
                *(float4*)(&qv[0]) = *(const float4*)(qrow + i * 8);
                *(float4*)(&qv[4]) = *(const float4*)(qrow + i * 8 + 4);
                unsigned short ps[8];
                *(uint4*)ps = pv;
                unsigned short ob[8];
                #pragma unroll
                for (int j = 0; j < 8; ++j)
                    ob[j] = f2bf(fmaxf(qv[j] + bf2f(ps[j]), 0.f));
                int slot = half * 16 + i;
                Ash[row * 32 + (slot ^ (row & 31))] = *(uint4*)ob;
            }
        }
        __syncthreads();

        // ---- 128x128x256 MFMA GEMM: wave w covers all 128 rows x its 32 cols ----
        f32x4 acc[8][2];
        #pragma unroll
        for (int mt = 0; mt < 8; ++mt) {
            acc[mt][0] = (f32x4){0.f, 0.f, 0.f, 0.f};
            acc[mt][1] = (f32x4){0.f, 0.f, 0.f, 0.f};
        }
        #pragma unroll
        for (int ks = 0; ks < 8; ++ks) {
            bf16x8 af[8];
            #pragma unroll
            for (int mt = 0; mt < 8; ++mt) {
                int ar = mt * 16 + l15;
                int slot = ks * 4 + l4;
                af[mt] = *(const bf16x8*)&Ash[ar * 32 + (slot ^ (ar & 31))];
            }
            #pragma unroll
            for (int mt = 0; mt < 8; ++mt) {
                #pragma unroll
                for (int nt = 0; nt < 2; ++nt)
                    acc[mt][nt] = __builtin_amdgcn_mfma_f32_16x16x32_bf16(
                        af[mt], breg[ks][nt], acc[mt][nt], 0, 0, 0);
            }
        }

        // ---- per-row partial score over this wave's 32 cols ----
        #pragma unroll
        for (int mt = 0; mt < 8; ++mt) {
            #pragma unroll
            for (int j = 0; j < 4; ++j) {
                float sp = fmaxf(acc[mt][0][j] + b2v[0], 0.f) * w3v[0]
                         + fmaxf(acc[mt][1][j] + b2v[1], 0.f) * w3v[1];
                sp += __shfl_xor(sp, 1, 16);
                sp += __shfl_xor(sp, 2, 16);
                sp += __shfl_xor(sp, 4, 16);
                sp += __shfl_xor(sp, 8, 16);
                if (l15 == 0) spart[w][mt * 16 + l4 * 4 + j] = sp;
            }
        }
        __syncthreads();

        // ---- softmax over K=8 per c, then distance via Gram expansion ----
        if (t < 128) {                      // waves 0,1 fully active (no divergence)
            int c = t >> 3, k = t & 7;
            float s = spart[0][t] + spart[1][t] + spart[2][t] + spart[3][t];
            float mx = s;
            mx = fmaxf(mx, __shfl_xor(mx, 1, 8));
            mx = fmaxf(mx, __shfl_xor(mx, 2, 8));
            mx = fmaxf(mx, __shfl_xor(mx, 4, 8));
            float e = __expf(s - mx);
            float den = e;
            den += __shfl_xor(den, 1, 8);
            den += __shfl_xor(den, 2, 8);
            den += __shfl_xor(den, 4, 8);
            float a = e / den;
            float p2 = a * sqp[m * CK + t];
            float p3 = 0.f;
            #pragma unroll
            for (int kq = 0; kq < 8; ++kq) {
                float ak = __shfl(a, kq, 8);
                p3 = fmaf(ak, G[c * 64 + kq * 8 + k], p3);
            }
            p3 *= a;
            float pr = p3 - 2.f * p2;
            pr += __shfl_xor(pr, 1, 8);
            pr += __shfl_xor(pr, 2, 8);
            pr += __shfl_xor(pr, 4, 8);
            if (k == 0) {
                float d2 = q2[m] + pr;
                out[m * NC + c] = -sqrtf(fmaxf(d2, 0.f));
            }
        }
        __syncthreads();
    }
}

extern "C" void kernel_launch(void* const* d_in, const int* in_sizes, int n_in,
                              void* d_out, int out_size, void* d_ws, size_t ws_size,
                              hipStream_t stream) {
    const float* query = (const float*)d_in[0];
    const float* prot  = (const float*)d_in[1];
    const float* W1    = (const float*)d_in[2];
    const float* b1    = (const float*)d_in[3];
    const float* W2    = (const float*)d_in[4];
    const float* b2    = (const float*)d_in[5];
    const float* W3    = (const float*)d_in[6];
    // b3 (d_in[7]) is softmax-shift-invariant and a constant offset pre-softmax: unused.

    char* ws = (char*)d_ws;
    float*          qh  = (float*)(ws);                    // 2048*256*4  = 2097152
    float*          sqp = (float*)(ws + 2097152);          // 2048*128*4  = 1048576
    float*          q2  = (float*)(ws + 3145728);          // 2048*4      = 8192
    float*          G   = (float*)(ws + 3153920);          // 1024*4      = 4096
    unsigned short* php = (unsigned short*)(ws + 3158016); // 128*256*2   = 65536
    unsigned short* w2t = (unsigned short*)(ws + 3223552); // 128*256*2   = 65536
    float* out = (float*)d_out;

    prep0<<<388, 256, 0, stream>>>(query, prot, W2, w2t, G, q2);
    prep1<<<400, 256, 0, stream>>>(query, prot, W1, b1, qh, php, sqp);
    fused2<<<512, 256, 0, stream>>>(qh, php, w2t, sqp, q2, G, b2, W3, out);
}

// Round 2
// 104.726 us; speedup vs baseline: 2.0607x; 2.0607x over previous
//
#include <hip/hip_runtime.h>
#include <hip/hip_bf16.h>
#include <cstdint>

#define NC 16
#define CK 128

typedef __attribute__((ext_vector_type(8))) short bf16x8;
typedef __attribute__((ext_vector_type(4))) float f32x4;

__device__ __forceinline__ unsigned short f2bf(float f) {
    union { __bf16 b; unsigned short s; } u;
    u.b = (__bf16)f;
    return u.s;
}
__device__ __forceinline__ float bf2f(unsigned short s) {
    union { __bf16 b; unsigned short s; } u;
    u.s = s;
    return (float)u.b;
}

// ---------------- prepA: bf16 converts + transposes + Gram + ||q||^2 ----------------
__global__ void prepA(const float* __restrict__ query,
                      const float* __restrict__ prot,
                      const float* __restrict__ W1,
                      const float* __restrict__ W2,
                      unsigned short* __restrict__ q_bf,
                      unsigned short* __restrict__ prot_bf,
                      unsigned short* __restrict__ w1t,
                      unsigned short* __restrict__ w2t,
                      float* __restrict__ G,
                      float* __restrict__ q2) {
    int b = blockIdx.x, t = threadIdx.x;
    if (b < 256) {
        // q_bf: 2048x256
        int i0 = (b * 256 + t) * 8;
        float4 a = *(const float4*)(query + i0);
        float4 c = *(const float4*)(query + i0 + 4);
        unsigned short o[8] = { f2bf(a.x), f2bf(a.y), f2bf(a.z), f2bf(a.w),
                                f2bf(c.x), f2bf(c.y), f2bf(c.z), f2bf(c.w) };
        *(uint4*)(q_bf + i0) = *(const uint4*)o;
    } else if (b < 272) {
        // prot_bf: 128x256
        int i0 = ((b - 256) * 256 + t) * 8;
        float4 a = *(const float4*)(prot + i0);
        float4 c = *(const float4*)(prot + i0 + 4);
        unsigned short o[8] = { f2bf(a.x), f2bf(a.y), f2bf(a.z), f2bf(a.w),
                                f2bf(c.x), f2bf(c.y), f2bf(c.z), f2bf(c.w) };
        *(uint4*)(prot_bf + i0) = *(const uint4*)o;
    } else if (b < 288) {
        // w2t[n][k] = W2[k][n] bf16 : 128x256
        int e = (b - 272) * 256 + t;       // 0..4095
        int n = e >> 5, k0 = (e & 31) * 8;
        unsigned short o[8];
        #pragma unroll
        for (int j = 0; j < 8; ++j) o[j] = f2bf(W2[(k0 + j) * 128 + n]);
        *(uint4*)(w2t + n * 256 + k0) = *(const uint4*)o;
    } else if (b < 352) {
        // w1t[s*256+col][d] = W1[s*256+d][col] bf16 : 512x256
        int e = (b - 288) * 256 + t;       // 0..16383
        int hp = e >> 5, d0 = (e & 31) * 8;
        int s = hp >> 8, col = hp & 255;
        unsigned short o[8];
        #pragma unroll
        for (int j = 0; j < 8; ++j) o[j] = f2bf(W1[(s * 256 + d0 + j) * 256 + col]);
        *(uint4*)(w1t + hp * 256 + d0) = *(const uint4*)o;
    } else if (b < 356) {
        // Gram: G[c][k][kp]
        int g = (b - 352) * 256 + t;       // 0..1023
        int c = g >> 6, k = (g >> 3) & 7, kp = g & 7;
        const float4* pa = (const float4*)(prot + (c * 8 + k) * 256);
        const float4* pb = (const float4*)(prot + (c * 8 + kp) * 256);
        float s = 0.f;
        for (int i = 0; i < 64; ++i) {
            float4 x = pa[i], y = pb[i];
            s += x.x * y.x + x.y * y.y + x.z * y.z + x.w * y.w;
        }
        G[g] = s;
    } else {
        // q2[m]: 256 blocks x 8 m
        int bb = b - 356;
        int m = bb * 8 + (t >> 5), l = t & 31;
        const float4* qp = (const float4*)(query + m * 256 + l * 8);
        float4 a = qp[0], c4 = qp[1];
        float s = a.x * a.x + a.y * a.y + a.z * a.z + a.w * a.w
                + c4.x * c4.x + c4.y * c4.y + c4.z * c4.z + c4.w * c4.w;
        for (int off = 1; off < 32; off <<= 1) s += __shfl_xor(s, off, 32);
        if (l == 0) q2[m] = s;
    }
}

// ---------------- prepB: MFMA GEMMs: qh = q@Wq, sqp = q@P^T, php = P@Wp + b1 --------
__global__ __launch_bounds__(256, 2)
void prepB(const unsigned short* __restrict__ q_bf,
           const unsigned short* __restrict__ prot_bf,
           const unsigned short* __restrict__ w1t,
           const float* __restrict__ b1,
           float* __restrict__ qh,
           float* __restrict__ sqp,
           unsigned short* __restrict__ php) {
    int b = blockIdx.x, t = threadIdx.x;
    int w = t >> 6, l = t & 63, l15 = l & 15, l4 = l >> 4;
    const unsigned short *A, *B;
    int row0, col0, mode;
    if (b < 64)      { mode = 0; row0 = (b >> 2) * 128; col0 = (b & 3) * 64;  A = q_bf;    B = w1t; }
    else if (b < 96) { int bb = b - 64; mode = 1; row0 = (bb >> 1) * 128; col0 = (bb & 1) * 64; A = q_bf; B = prot_bf; }
    else             { int bb = b - 96; mode = 2; row0 = 0; col0 = bb * 64;   A = prot_bf; B = w1t + 65536; }

    bf16x8 breg[8][4];
    #pragma unroll
    for (int ks = 0; ks < 8; ++ks)
        #pragma unroll
        for (int nt = 0; nt < 4; ++nt)
            breg[ks][nt] = *(const bf16x8*)(B + (col0 + nt * 16 + l15) * 256 + ks * 32 + l4 * 8);

    f32x4 acc[2][4];
    #pragma unroll
    for (int mt = 0; mt < 2; ++mt)
        #pragma unroll
        for (int nt = 0; nt < 4; ++nt) acc[mt][nt] = (f32x4){0.f, 0.f, 0.f, 0.f};

    #pragma unroll
    for (int ks = 0; ks < 8; ++ks) {
        bf16x8 af[2];
        #pragma unroll
        for (int mt = 0; mt < 2; ++mt)
            af[mt] = *(const bf16x8*)(A + (row0 + w * 32 + mt * 16 + l15) * 256 + ks * 32 + l4 * 8);
        #pragma unroll
        for (int mt = 0; mt < 2; ++mt)
            #pragma unroll
            for (int nt = 0; nt < 4; ++nt)
                acc[mt][nt] = __builtin_amdgcn_mfma_f32_16x16x32_bf16(
                    af[mt], breg[ks][nt], acc[mt][nt], 0, 0, 0);
    }

    #pragma unroll
    for (int mt = 0; mt < 2; ++mt)
        #pragma unroll
        for (int nt = 0; nt < 4; ++nt)
            #pragma unroll
            for (int j = 0; j < 4; ++j) {
                int r = row0 + w * 32 + mt * 16 + l4 * 4 + j;
                int cc = col0 + nt * 16 + l15;
                float v = acc[mt][nt][j];
                if (mode == 0)      qh[r * 256 + cc] = v;
                else if (mode == 1) sqp[r * 128 + cc] = v;
                else                php[r * 256 + cc] = f2bf(v + b1[cc]);
            }
}

// ---------------- fused2: A-build + MFMA + scores/softmax/distance -------------------
__global__ __launch_bounds__(512, 2)
void fused2(const float* __restrict__ qh,
            const unsigned short* __restrict__ php,
            const unsigned short* __restrict__ w2t,
            const float* __restrict__ sqp,
            const float* __restrict__ q2,
            const float* __restrict__ G,
            const float* __restrict__ b2,
            const float* __restrict__ W3,
            float* __restrict__ out) {
    __shared__ uint4 Ash[2][4096];          // 2 x (128 rows x 256 bf16), swizzled
    __shared__ float spart[2][2][128];      // [buf][col-strip][row]

    int t = threadIdx.x;
    int w = t >> 6, l = t & 63, l15 = l & 15, l4 = l >> 4;
    int rg = w >> 1, cs = w & 1;            // wave = rows rg*32..+32 x cols cs*64..+64
    int brow = t & 127, seg = t >> 7;       // builder: row brow, cols seg*64..+64

    // php row-segment in registers (once per block)
    bf16x8 phpreg[8];
    #pragma unroll
    for (int i = 0; i < 8; ++i)
        phpreg[i] = *(const bf16x8*)(php + brow * 256 + seg * 64 + i * 8);

    // W2^T fragments in registers (once per block)
    bf16x8 breg[8][4];
    #pragma unroll
    for (int ks = 0; ks < 8; ++ks)
        #pragma unroll
        for (int nt = 0; nt < 4; ++nt)
            breg[ks][nt] = *(const bf16x8*)(w2t + (cs * 64 + nt * 16 + l15) * 256 + ks * 32 + l4 * 8);

    float b2v[4], w3v[4];
    #pragma unroll
    for (int nt = 0; nt < 4; ++nt) {
        int col = cs * 64 + nt * 16 + l15;
        b2v[nt] = b2[col];
        w3v[nt] = W3[col];
    }

    int m0 = blockIdx.x * 8;

    auto buildA = [&](int buf, int m) {
        const float* qrow = qh + m * 256 + seg * 64;
        #pragma unroll
        for (int i = 0; i < 8; ++i) {
            float4 qa = *(const float4*)(qrow + i * 8);
            float4 qb = *(const float4*)(qrow + i * 8 + 4);
            float qv[8] = { qa.x, qa.y, qa.z, qa.w, qb.x, qb.y, qb.z, qb.w };
            bf16x8 pv = phpreg[i];
            unsigned short ob[8];
            #pragma unroll
            for (int j = 0; j < 8; ++j)
                ob[j] = f2bf(fmaxf(qv[j] + bf2f((unsigned short)pv[j]), 0.f));
            int slot = seg * 8 + i;
            Ash[buf][brow * 32 + (slot ^ (brow & 31))] = *(const uint4*)ob;
        }
    };

    buildA(0, m0);
    __syncthreads();

    for (int g = 0; g < 8; ++g) {
        int cur = g & 1;
        int m = m0 + g;

        if (g < 7) buildA(cur ^ 1, m + 1);   // overlap next build with this MFMA

        f32x4 acc[2][4];
        #pragma unroll
        for (int mt = 0; mt < 2; ++mt)
            #pragma unroll
            for (int nt = 0; nt < 4; ++nt) acc[mt][nt] = (f32x4){0.f, 0.f, 0.f, 0.f};

        #pragma unroll
        for (int ks = 0; ks < 8; ++ks) {
            bf16x8 af[2];
            #pragma unroll
            for (int mt = 0; mt < 2; ++mt) {
                int ar = rg * 32 + mt * 16 + l15;
                int slot = ks * 4 + l4;
                af[mt] = *(const bf16x8*)&Ash[cur][ar * 32 + (slot ^ (ar & 31))];
            }
            #pragma unroll
            for (int mt = 0; mt < 2; ++mt)
                #pragma unroll
                for (int nt = 0; nt < 4; ++nt)
                    acc[mt][nt] = __builtin_amdgcn_mfma_f32_16x16x32_bf16(
                        af[mt], breg[ks][nt], acc[mt][nt], 0, 0, 0);
        }

        // partial scores over this wave's 64 cols
        #pragma unroll
        for (int mt = 0; mt < 2; ++mt)
            #pragma unroll
            for (int j = 0; j < 4; ++j) {
                float sp = fmaxf(acc[mt][0][j] + b2v[0], 0.f) * w3v[0]
                         + fmaxf(acc[mt][1][j] + b2v[1], 0.f) * w3v[1]
                         + fmaxf(acc[mt][2][j] + b2v[2], 0.f) * w3v[2]
                         + fmaxf(acc[mt][3][j] + b2v[3], 0.f) * w3v[3];
                sp += __shfl_xor(sp, 1, 16);
                sp += __shfl_xor(sp, 2, 16);
                sp += __shfl_xor(sp, 4, 16);
                sp += __shfl_xor(sp, 8, 16);
                if (l15 == 0) spart[cur][cs][rg * 32 + mt * 16 + l4 * 4 + j] = sp;
            }
        __syncthreads();

        // softmax over K=8 per c, distance via Gram expansion
        if (t < 128) {
            int c = t >> 3, k = t & 7;
            float s = spart[cur][0][t] + spart[cur][1][t];
            float mx = s;
            mx = fmaxf(mx, __shfl_xor(mx, 1, 8));
            mx = fmaxf(mx, __shfl_xor(mx, 2, 8));
            mx = fmaxf(mx, __shfl_xor(mx, 4, 8));
            float e = __expf(s - mx);
            float den = e;
            den += __shfl_xor(den, 1, 8);
            den += __shfl_xor(den, 2, 8);
            den += __shfl_xor(den, 4, 8);
            float a = e / den;
            float p2 = a * sqp[m * CK + t];
            float p3 = 0.f;
            #pragma unroll
            for (int kq = 0; kq < 8; ++kq) {
                float ak = __shfl(a, kq, 8);
                p3 = fmaf(ak, G[c * 64 + kq * 8 + k], p3);
            }
            p3 *= a;
            float pr = p3 - 2.f * p2;
            pr += __shfl_xor(pr, 1, 8);
            pr += __shfl_xor(pr, 2, 8);
            pr += __shfl_xor(pr, 4, 8);
            if (k == 0) {
                float d2 = q2[m] + pr;
                out[m * NC + c] = -sqrtf(fmaxf(d2, 0.f));
            }
        }
    }
}

extern "C" void kernel_launch(void* const* d_in, const int* in_sizes, int n_in,
                              void* d_out, int out_size, void* d_ws, size_t ws_size,
                              hipStream_t stream) {
    const float* query = (const float*)d_in[0];
    const float* prot  = (const float*)d_in[1];
    const float* W1    = (const float*)d_in[2];
    const float* b1    = (const float*)d_in[3];
    const float* W2    = (const float*)d_in[4];
    const float* b2    = (const float*)d_in[5];
    const float* W3    = (const float*)d_in[6];
    // b3 (d_in[7]): constant shift pre-softmax -> softmax-invariant: unused.

    char* ws = (char*)d_ws;
    float*          qh      = (float*)(ws);                    // 2 MB
    float*          sqp     = (float*)(ws + 2097152);          // 1 MB
    float*          q2      = (float*)(ws + 3145728);          // 8 KB
    float*          G       = (float*)(ws + 3153920);          // 4 KB
    unsigned short* php     = (unsigned short*)(ws + 3158016); // 64 KB
    unsigned short* w2t     = (unsigned short*)(ws + 3223552); // 64 KB
    unsigned short* q_bf    = (unsigned short*)(ws + 3289088); // 1 MB
    unsigned short* prot_bf = (unsigned short*)(ws + 4337664); // 64 KB
    unsigned short* w1t     = (unsigned short*)(ws + 4403200); // 256 KB
    float* out = (float*)d_out;

    prepA<<<612, 256, 0, stream>>>(query, prot, W1, W2, q_bf, prot_bf, w1t, w2t, G, q2);
    prepB<<<100, 256, 0, stream>>>(q_bf, prot_bf, w1t, b1, qh, sqp, php);
    fused2<<<256, 512, 0, stream>>>(qh, php, w2t, sqp, q2, G, b2, W3, out);
}

// Round 4
// 49.390 us; speedup vs baseline: 4.3695x; 2.1204x over previous
//
#include <hip/hip_runtime.h>
#include <hip/hip_fp16.h>
#include <cstdint>

typedef __attribute__((ext_vector_type(8))) _Float16 f16x8;
typedef __attribute__((ext_vector_type(4))) float f32x4;

__device__ __forceinline__ f16x8 cvt8(float4 x, float4 y) {
    f16x8 r;
    r[0] = (_Float16)x.x; r[1] = (_Float16)x.y; r[2] = (_Float16)x.z; r[3] = (_Float16)x.w;
    r[4] = (_Float16)y.x; r[5] = (_Float16)y.y; r[6] = (_Float16)y.z; r[7] = (_Float16)y.w;
    return r;
}

__device__ __forceinline__ f16x8 relu8(f16x8 v) {
    f16x8 z = {};
    return __builtin_elementwise_max(v, z);   // v_pk_max_f16
}

// =============== prep: all GEMMs (f16 MFMA, f32 in) + packs + Gram + ||q||^2 ===============
// blocks [0,64):   qh16 = q@Wq            (2048x256)
// blocks [64,96):  sqp  = q@P^T  (f32)    (2048x128)
// blocks [96,100): phpk = P@Wp + b1       (128x256, fragment layout [kb][row])
// blocks [100,116): w2pack[kb][col] = W2[kb*8+j][col] f16 chunks
// blocks [116,120): Gram G[c][k][kp]
// blocks [120,376): q2[m]
__global__ __launch_bounds__(256)
void prep(const float* __restrict__ query,
          const float* __restrict__ prot,
          const float* __restrict__ W1,
          const float* __restrict__ b1,
          const float* __restrict__ W2,
          _Float16* __restrict__ qh16,
          _Float16* __restrict__ phps,
          f16x8* __restrict__ w2pack,
          float* __restrict__ sqp,
          float* __restrict__ q2,
          float* __restrict__ Gm) {
    int b = blockIdx.x, t = threadIdx.x;
    if (b < 100) {
        int mode, rb, cstrip;
        if (b < 64)      { mode = 0; rb = (b >> 2) * 128;        cstrip = (b & 3) * 64; }
        else if (b < 96) { int bb = b - 64; mode = 1; rb = (bb >> 1) * 128; cstrip = (bb & 1) * 64; }
        else             { int bb = b - 96; mode = 2; rb = 0;    cstrip = bb * 64; }
        int w = t >> 6, l = t & 63, l15 = l & 15, l4 = l >> 4;
        const float* Asrc = (mode == 2) ? prot : query;

        f32x4 acc[2][4];
        #pragma unroll
        for (int mtt = 0; mtt < 2; ++mtt)
            #pragma unroll
            for (int nt = 0; nt < 4; ++nt) acc[mtt][nt] = (f32x4){0.f, 0.f, 0.f, 0.f};

        for (int ks = 0; ks < 8; ++ks) {
            f16x8 af[2];
            #pragma unroll
            for (int mtt = 0; mtt < 2; ++mtt) {
                int row = rb + w * 32 + mtt * 16 + l15;
                const float* ap = Asrc + row * 256 + ks * 32 + l4 * 8;
                af[mtt] = cvt8(*(const float4*)ap, *(const float4*)(ap + 4));
            }
            f16x8 bf[4];
            if (mode == 1) {
                #pragma unroll
                for (int nt = 0; nt < 4; ++nt) {
                    int col = cstrip + nt * 16 + l15;
                    const float* bp = prot + col * 256 + ks * 32 + l4 * 8;
                    bf[nt] = cvt8(*(const float4*)bp, *(const float4*)(bp + 4));
                }
            } else {
                int koff = (mode == 2 ? 256 : 0) + ks * 32 + l4 * 8;
                #pragma unroll
                for (int nt = 0; nt < 4; ++nt) {
                    int col = cstrip + nt * 16 + l15;
                    #pragma unroll
                    for (int j = 0; j < 8; ++j)
                        bf[nt][j] = (_Float16)W1[(koff + j) * 256 + col];
                }
            }
            #pragma unroll
            for (int mtt = 0; mtt < 2; ++mtt)
                #pragma unroll
                for (int nt = 0; nt < 4; ++nt)
                    acc[mtt][nt] = __builtin_amdgcn_mfma_f32_16x16x32_f16(
                        af[mtt], bf[nt], acc[mtt][nt], 0, 0, 0);
        }
        #pragma unroll
        for (int mtt = 0; mtt < 2; ++mtt)
            #pragma unroll
            for (int nt = 0; nt < 4; ++nt)
                #pragma unroll
                for (int j = 0; j < 4; ++j) {
                    int row = rb + w * 32 + mtt * 16 + l4 * 4 + j;
                    int col = cstrip + nt * 16 + l15;
                    float v = acc[mtt][nt][j];
                    if (mode == 0)      qh16[row * 256 + col] = (_Float16)v;
                    else if (mode == 1) sqp[row * 128 + col] = v;
                    else                phps[((col >> 3) * 128 + row) * 8 + (col & 7)] =
                                            (_Float16)(v + b1[col]);
                }
    } else if (b < 116) {
        int chunk = (b - 100) * 256 + t;          // 0..4095
        int kb = chunk >> 7, col = chunk & 127;
        f16x8 o;
        #pragma unroll
        for (int j = 0; j < 8; ++j) o[j] = (_Float16)W2[(kb * 8 + j) * 128 + col];
        w2pack[chunk] = o;
    } else if (b < 120) {
        int g = (b - 116) * 256 + t;              // 0..1023
        int c = g >> 6, k = (g >> 3) & 7, kp = g & 7;
        const float4* pa = (const float4*)(prot + (c * 8 + k) * 256);
        const float4* pb = (const float4*)(prot + (c * 8 + kp) * 256);
        float s = 0.f;
        for (int i = 0; i < 64; ++i) {
            float4 x = pa[i], y = pb[i];
            s += x.x * y.x + x.y * y.y + x.z * y.z + x.w * y.w;
        }
        Gm[g] = s;
    } else {
        int bb = b - 120;                          // 0..255
        int m = bb * 8 + (t >> 5), lane = t & 31;
        const float4* qp = (const float4*)(query + m * 256 + lane * 8);
        float4 a = qp[0], c4 = qp[1];
        float s = a.x * a.x + a.y * a.y + a.z * a.z + a.w * a.w
                + c4.x * c4.x + c4.y * c4.y + c4.z * c4.z + c4.w * c4.w;
        for (int off = 1; off < 32; off <<= 1) s += __shfl_xor(s, off, 32);
        if (lane == 0) q2[m] = s;
    }
}

// =============== fused2: A-in-regs, W2-in-LDS, 1 barrier per m ===============
// Block: 256 thr = 4 waves {rg,cs}; covers 64 rows (half of CK) x 128 cols, 8 m's.
// grid = 2 rowhalves x 256 mgroups = 512 blocks = 2 blocks/CU.
__global__ __launch_bounds__(256, 2)
void fused2(const _Float16* __restrict__ qh16,
            const f16x8* __restrict__ phpk,
            const f16x8* __restrict__ w2pack,
            const float* __restrict__ sqp,
            const float* __restrict__ q2,
            const float* __restrict__ Gm,
            const float* __restrict__ b2,
            const float* __restrict__ W3,
            float* __restrict__ out) {
    __shared__ f16x8 w2l[4096];                 // [kb=32][col=128] chunks, 64 KB
    __shared__ float spart[2][2][64];           // [parity][cs][row]

    int t = threadIdx.x;
    int w = t >> 6, l = t & 63, l15 = l & 15, l4 = l >> 4;
    int rg = w >> 1, cs = w & 1;
    int rh = blockIdx.x & 1;
    int mg = blockIdx.x >> 1;

    #pragma unroll
    for (int i = 0; i < 16; ++i)
        w2l[t + i * 256] = w2pack[t + i * 256];

    // php fragments for this wave's 32 rows (m-invariant, stay in regs)
    f16x8 ph[8][2];
    #pragma unroll
    for (int ks = 0; ks < 8; ++ks)
        #pragma unroll
        for (int mtt = 0; mtt < 2; ++mtt)
            ph[ks][mtt] = phpk[(ks * 4 + l4) * 128 + rh * 64 + rg * 32 + mtt * 16 + l15];

    float b2v[4], w3v[4];
    #pragma unroll
    for (int nt = 0; nt < 4; ++nt) {
        int col = cs * 64 + nt * 16 + l15;
        b2v[nt] = b2[col];
        w3v[nt] = W3[col];
    }

    __syncthreads();

    int m0 = mg * 8;
    f16x8 qv[8];
    #pragma unroll
    for (int ks = 0; ks < 8; ++ks)
        qv[ks] = *(const f16x8*)(qh16 + m0 * 256 + (ks * 4 + l4) * 8);

    for (int g = 0; g < 8; ++g) {
        int m = m0 + g;

        f32x4 acc[2][4];
        #pragma unroll
        for (int mtt = 0; mtt < 2; ++mtt)
            #pragma unroll
            for (int nt = 0; nt < 4; ++nt) acc[mtt][nt] = (f32x4){0.f, 0.f, 0.f, 0.f};

        #pragma unroll
        for (int ks = 0; ks < 8; ++ks) {
            f16x8 a0 = relu8(qv[ks] + ph[ks][0]);
            f16x8 a1 = relu8(qv[ks] + ph[ks][1]);
            #pragma unroll
            for (int nt = 0; nt < 4; ++nt) {
                f16x8 bf = w2l[(ks * 4 + l4) * 128 + cs * 64 + nt * 16 + l15];
                acc[0][nt] = __builtin_amdgcn_mfma_f32_16x16x32_f16(a0, bf, acc[0][nt], 0, 0, 0);
                acc[1][nt] = __builtin_amdgcn_mfma_f32_16x16x32_f16(a1, bf, acc[1][nt], 0, 0, 0);
            }
        }

        // prefetch next m's qh row under the epilogue
        if (g < 7) {
            #pragma unroll
            for (int ks = 0; ks < 8; ++ks)
                qv[ks] = *(const f16x8*)(qh16 + (m + 1) * 256 + (ks * 4 + l4) * 8);
        }

        // partial scores over this wave's 64 cols
        #pragma unroll
        for (int mtt = 0; mtt < 2; ++mtt)
            #pragma unroll
            for (int j = 0; j < 4; ++j) {
                float sp = fmaxf(acc[mtt][0][j] + b2v[0], 0.f) * w3v[0]
                         + fmaxf(acc[mtt][1][j] + b2v[1], 0.f) * w3v[1]
                         + fmaxf(acc[mtt][2][j] + b2v[2], 0.f) * w3v[2]
                         + fmaxf(acc[mtt][3][j] + b2v[3], 0.f) * w3v[3];
                sp += __shfl_xor(sp, 1, 16);
                sp += __shfl_xor(sp, 2, 16);
                sp += __shfl_xor(sp, 4, 16);
                sp += __shfl_xor(sp, 8, 16);
                if (l15 == 0) spart[g & 1][cs][rg * 32 + mtt * 16 + l4 * 4 + j] = sp;
            }
        __syncthreads();

        // softmax over K=8 per c + Gram-expanded distance (wave 0 only, no divergence)
        if (t < 64) {
            int c = t >> 3, k = t & 7;
            float s = spart[g & 1][0][t] + spart[g & 1][1][t];
            float mx = s;
            mx = fmaxf(mx, __shfl_xor(mx, 1, 8));
            mx = fmaxf(mx, __shfl_xor(mx, 2, 8));
            mx = fmaxf(mx, __shfl_xor(mx, 4, 8));
            float e = __expf(s - mx);
            float den = e;
            den += __shfl_xor(den, 1, 8);
            den += __shfl_xor(den, 2, 8);
            den += __shfl_xor(den, 4, 8);
            float a = e / den;
            float p2 = a * sqp[m * 128 + rh * 64 + t];
            float p3 = 0.f;
            #pragma unroll
            for (int kq = 0; kq < 8; ++kq) {
                float ak = __shfl(a, kq, 8);
                p3 = fmaf(ak, Gm[(rh * 8 + c) * 64 + kq * 8 + k], p3);
            }
            p3 *= a;
            float pr = p3 - 2.f * p2;
            pr += __shfl_xor(pr, 1, 8);
            pr += __shfl_xor(pr, 2, 8);
            pr += __shfl_xor(pr, 4, 8);
            if (k == 0)
                out[m * 16 + rh * 8 + c] = -sqrtf(fmaxf(q2[m] + pr, 0.f));
        }
    }
}

extern "C" void kernel_launch(void* const* d_in, const int* in_sizes, int n_in,
                              void* d_out, int out_size, void* d_ws, size_t ws_size,
                              hipStream_t stream) {
    const float* query = (const float*)d_in[0];
    const float* prot  = (const float*)d_in[1];
    const float* W1    = (const float*)d_in[2];
    const float* b1    = (const float*)d_in[3];
    const float* W2    = (const float*)d_in[4];
    const float* b2    = (const float*)d_in[5];
    const float* W3    = (const float*)d_in[6];
    // b3 (d_in[7]): constant pre-softmax shift -> softmax-invariant: unused.

    char* ws = (char*)d_ws;
    _Float16* qh16   = (_Float16*)(ws);                 // 1 MB
    _Float16* phps   = (_Float16*)(ws + 1048576);       // 64 KB (fragment layout)
    f16x8*    w2pack = (f16x8*)(ws + 1114112);          // 64 KB
    float*    sqp    = (float*)(ws + 1179648);          // 1 MB
    float*    q2     = (float*)(ws + 2228224);          // 8 KB
    float*    Gm     = (float*)(ws + 2236416);          // 4 KB
    float* out = (float*)d_out;

    prep<<<376, 256, 0, stream>>>(query, prot, W1, b1, W2,
                                  qh16, phps, w2pack, sqp, q2, Gm);
    fused2<<<512, 256, 0, stream>>>(qh16, (const f16x8*)phps, (const f16x8*)w2pack,
                                    sqp, q2, Gm, b2, W3, out);
}